// Round 1
// baseline (5688.590 us; speedup 1.0000x reference)
//
#include <hip/hip_runtime.h>

#define NN 100000
#define NF 128
#define NE 1600000

// ---------------------------------------------------------------- out-degree
__global__ __launch_bounds__(256) void k_deg(const int* __restrict__ src,
                                             int* __restrict__ deg) {
  int e = blockIdx.x * 256 + threadIdx.x;
  if (e < NE) atomicAdd(&deg[src[e]], 1);
}

// ------------------------------------------------- scatter-add aggregation
// 32 threads per edge, each handles 4 consecutive floats (float4 gather).
__global__ __launch_bounds__(256) void k_scatter(const float* __restrict__ feat,
                                                 const int* __restrict__ src,
                                                 const int* __restrict__ dst,
                                                 float* __restrict__ agg) {
  int t = blockIdx.x * 256 + threadIdx.x;
  int e = t >> 5;
  if (e >= NE) return;
  int c = (t & 31) * 4;
  int s = src[e], d = dst[e];
  const float4 v = *reinterpret_cast<const float4*>(feat + (size_t)s * NF + c);
  float* o = agg + (size_t)d * NF + c;
  atomicAdd(o + 0, v.x);
  atomicAdd(o + 1, v.y);
  atomicAdd(o + 2, v.z);
  atomicAdd(o + 3, v.w);
}

// ---------------------------------------------------------------- fused GEMM
// out[i][j] = relu( sum_k A1[i][k]*B1[j][k] + sum_k A2[i][k]*B2[j][k] + bias[j] )
// Treated as K=256 GEMM: A' = [A1|A2] (Nx256), B' = [B1|B2] (128x256).
// Tile: 64 nodes x 128 outputs, BK=32, 256 threads, 32 acc/thread.
// In-place safe: each block reads only the A-rows it writes (epilogue after all loads).
template <int RELU>
__global__ __launch_bounds__(256) void k_gemm(const float* __restrict__ A1,
                                              const float* __restrict__ A2,
                                              const float* __restrict__ B1,
                                              const float* __restrict__ B2,
                                              const float* __restrict__ bias,
                                              float* __restrict__ out) {
  __shared__ __align__(16) float At[32][72];    // At[kk][i], stride 288B (16B mult)
  __shared__ __align__(16) float Bt[32][136];   // Bt[kk][j], stride 544B (16B mult)

  const int tid = threadIdx.x;
  const int n0 = blockIdx.x * 64;
  const int tx = tid & 15;   // output group: j = tx*4..+3 and 64+tx*4..+3
  const int ty = tid >> 4;   // node group: i = ty*4..+3

  float acc[4][8];
#pragma unroll
  for (int r = 0; r < 4; ++r)
#pragma unroll
    for (int c = 0; c < 8; ++c) acc[r][c] = 0.f;

  const int li = tid >> 2;  // A-load row 0..63
  const int lq = tid & 3;   // A-load k-chunk (8 floats)
  const int bj = tid >> 1;  // B-load row 0..127
  const int bh = tid & 1;   // B-load half (16 floats)

  for (int k0 = 0; k0 < 256; k0 += 32) {
    const float* __restrict__ A = (k0 < 128) ? A1 : A2;
    const float* __restrict__ B = (k0 < 128) ? B1 : B2;
    const int kb = k0 & 127;

    // A tile: 64 x 32 -> At transposed
    {
      float4 v0 = make_float4(0.f, 0.f, 0.f, 0.f), v1 = v0;
      const int node = n0 + li;
      if (node < NN) {
        const float* p = A + (size_t)node * NF + kb + lq * 8;
        v0 = *reinterpret_cast<const float4*>(p);
        v1 = *reinterpret_cast<const float4*>(p + 4);
      }
      const int kk = lq * 8;
      At[kk + 0][li] = v0.x; At[kk + 1][li] = v0.y;
      At[kk + 2][li] = v0.z; At[kk + 3][li] = v0.w;
      At[kk + 4][li] = v1.x; At[kk + 5][li] = v1.y;
      At[kk + 6][li] = v1.z; At[kk + 7][li] = v1.w;
    }
    // B tile: 128 x 32 -> Bt transposed
    {
      const float* p = B + (size_t)bj * NF + kb + bh * 16;
      const float4 w0 = *reinterpret_cast<const float4*>(p);
      const float4 w1 = *reinterpret_cast<const float4*>(p + 4);
      const float4 w2 = *reinterpret_cast<const float4*>(p + 8);
      const float4 w3 = *reinterpret_cast<const float4*>(p + 12);
      const int kk = bh * 16;
      Bt[kk + 0][bj] = w0.x;  Bt[kk + 1][bj] = w0.y;
      Bt[kk + 2][bj] = w0.z;  Bt[kk + 3][bj] = w0.w;
      Bt[kk + 4][bj] = w1.x;  Bt[kk + 5][bj] = w1.y;
      Bt[kk + 6][bj] = w1.z;  Bt[kk + 7][bj] = w1.w;
      Bt[kk + 8][bj] = w2.x;  Bt[kk + 9][bj] = w2.y;
      Bt[kk + 10][bj] = w2.z; Bt[kk + 11][bj] = w2.w;
      Bt[kk + 12][bj] = w3.x; Bt[kk + 13][bj] = w3.y;
      Bt[kk + 14][bj] = w3.z; Bt[kk + 15][bj] = w3.w;
    }
    __syncthreads();

#pragma unroll
    for (int kk = 0; kk < 32; ++kk) {
      const float4 a = *reinterpret_cast<const float4*>(&At[kk][ty * 4]);
      const float4 b0 = *reinterpret_cast<const float4*>(&Bt[kk][tx * 4]);
      const float4 b1 = *reinterpret_cast<const float4*>(&Bt[kk][64 + tx * 4]);
      const float av[4] = {a.x, a.y, a.z, a.w};
      const float bv[8] = {b0.x, b0.y, b0.z, b0.w, b1.x, b1.y, b1.z, b1.w};
#pragma unroll
      for (int r = 0; r < 4; ++r)
#pragma unroll
        for (int c = 0; c < 8; ++c) acc[r][c] += av[r] * bv[c];
    }
    __syncthreads();
  }

  // epilogue: bias + relu + store
  float bv[8];
#pragma unroll
  for (int c = 0; c < 4; ++c) {
    bv[c] = bias[tx * 4 + c];
    bv[4 + c] = bias[64 + tx * 4 + c];
  }
#pragma unroll
  for (int r = 0; r < 4; ++r) {
    const int node = n0 + ty * 4 + r;
    if (node < NN) {
      float4 o0, o1;
      o0.x = acc[r][0] + bv[0]; o0.y = acc[r][1] + bv[1];
      o0.z = acc[r][2] + bv[2]; o0.w = acc[r][3] + bv[3];
      o1.x = acc[r][4] + bv[4]; o1.y = acc[r][5] + bv[5];
      o1.z = acc[r][6] + bv[6]; o1.w = acc[r][7] + bv[7];
      if (RELU) {
        o0.x = fmaxf(o0.x, 0.f); o0.y = fmaxf(o0.y, 0.f);
        o0.z = fmaxf(o0.z, 0.f); o0.w = fmaxf(o0.w, 0.f);
        o1.x = fmaxf(o1.x, 0.f); o1.y = fmaxf(o1.y, 0.f);
        o1.z = fmaxf(o1.z, 0.f); o1.w = fmaxf(o1.w, 0.f);
      }
      float* po = out + (size_t)node * NF;
      *reinterpret_cast<float4*>(po + tx * 4) = o0;
      *reinterpret_cast<float4*>(po + 64 + tx * 4) = o1;
    }
  }
}

// ------------------------------------- layer-3 collapsed weighted reductions
// S[f]     = sum_i h[i][f]
// S[128+f] = sum_i deg[i] * h[i][f]
__global__ __launch_bounds__(256) void k_reduce3(const float* __restrict__ h,
                                                 const int* __restrict__ deg,
                                                 float* __restrict__ S) {
  const int t = blockIdx.x * 256 + threadIdx.x;  // 0..65535 (256 blocks)
  const int f = t & 127;
  const int i0 = t >> 7;  // 0..511
  float a1 = 0.f, a2 = 0.f;
  for (int i = i0; i < NN; i += 512) {
    const float v = h[(size_t)i * NF + f];
    a1 += v;
    a2 += (float)deg[i] * v;
  }
  atomicAdd(&S[f], a1);
  atomicAdd(&S[128 + f], a2);
}

__global__ __launch_bounds__(128) void k_final(const float* __restrict__ S,
                                               const float* __restrict__ W3rel,
                                               const float* __restrict__ W3root,
                                               const float* __restrict__ b3,
                                               float* __restrict__ out) {
  const int f = threadIdx.x;
  float v = W3rel[f] * S[128 + f] + W3root[f] * S[f];
#pragma unroll
  for (int o = 32; o > 0; o >>= 1) v += __shfl_down(v, o);
  __shared__ float tmp[2];
  if ((f & 63) == 0) tmp[f >> 6] = v;
  __syncthreads();
  if (f == 0) out[0] = (tmp[0] + tmp[1]) * (1.0f / NN) + b3[0];
}

// ---------------------------------------------------------------------------
extern "C" void kernel_launch(void* const* d_in, const int* in_sizes, int n_in,
                              void* d_out, int out_size, void* d_ws, size_t ws_size,
                              hipStream_t stream) {
  const float* x = (const float*)d_in[0];
  const int* ei = (const int*)d_in[1];
  const float* W1rel = (const float*)d_in[2];
  const float* b1 = (const float*)d_in[3];
  const float* W1root = (const float*)d_in[4];
  const float* W2rel = (const float*)d_in[5];
  const float* b2 = (const float*)d_in[6];
  const float* W2root = (const float*)d_in[7];
  const float* W3rel = (const float*)d_in[8];
  const float* b3 = (const float*)d_in[9];
  const float* W3root = (const float*)d_in[10];

  const int* src = ei;       // edge_index[0]
  const int* dst = ei + NE;  // edge_index[1]

  char* ws = (char*)d_ws;
  float* bufA = (float*)ws;                        // 51.2 MB
  float* bufB = (float*)(ws + 51200000);           // 51.2 MB
  int* deg = (int*)(ws + 102400000);               // 400 KB
  float* S = (float*)(ws + 102800000);             // 1 KB
  float* outp = (float*)d_out;

  const size_t featBytes = (size_t)NN * NF * sizeof(float);

  hipMemsetAsync(bufA, 0, featBytes, stream);
  hipMemsetAsync(deg, 0, (size_t)NN * sizeof(int), stream);
  hipMemsetAsync(S, 0, 256 * sizeof(float), stream);

  k_deg<<<(NE + 255) / 256, 256, 0, stream>>>(src, deg);

  // layer 1: agg(x) -> bufA; h1 = relu(gemm) in-place into bufA
  k_scatter<<<(NE * 32 + 255) / 256, 256, 0, stream>>>(x, src, dst, bufA);
  k_gemm<1><<<(NN + 63) / 64, 256, 0, stream>>>(bufA, x, W1rel, W1root, b1, bufA);

  // layer 2: agg(h1) -> bufB; h2 = relu(gemm) in-place into bufB
  hipMemsetAsync(bufB, 0, featBytes, stream);
  k_scatter<<<(NE * 32 + 255) / 256, 256, 0, stream>>>(bufA, src, dst, bufB);
  k_gemm<1><<<(NN + 63) / 64, 256, 0, stream>>>(bufB, bufA, W2rel, W2root, b2, bufB);

  // layer 3 collapsed: out = (W3rel . sum_i deg_i*h2_i + W3root . sum_i h2_i)/N + b3
  k_reduce3<<<256, 256, 0, stream>>>(bufB, deg, S);
  k_final<<<1, 128, 0, stream>>>(S, W3rel, W3root, b3, outp);
}

// Round 2
// 750.572 us; speedup vs baseline: 7.5790x; 7.5790x over previous
//
#include <hip/hip_runtime.h>

#define NN 100000
#define NF 128
#define NE 1600000
#define NB 391  // (NN+255)/256 scan blocks

// ---------------------------------------------------------------- histograms
__global__ __launch_bounds__(256) void k_hist(const int* __restrict__ dst,
                                              int* __restrict__ cnt) {
  int e = blockIdx.x * 256 + threadIdx.x;
  if (e < NE) atomicAdd(&cnt[dst[e]], 1);
}

__global__ __launch_bounds__(256) void k_deg(const int* __restrict__ src,
                                             int* __restrict__ deg) {
  int e = blockIdx.x * 256 + threadIdx.x;
  if (e < NE) atomicAdd(&deg[src[e]], 1);
}

// ------------------------------------------------- 2-level exclusive scan
// pass 1: per-block exclusive scan in place, emit block totals
__global__ __launch_bounds__(256) void k_scan1(int* __restrict__ cnt,
                                               int* __restrict__ bsum) {
  const int idx = blockIdx.x * 256 + threadIdx.x;
  const int v = (idx < NN) ? cnt[idx] : 0;
  const int lane = threadIdx.x & 63;
  const int w = threadIdx.x >> 6;
  int s = v;
#pragma unroll
  for (int o = 1; o < 64; o <<= 1) {
    int u = __shfl_up(s, o);
    if (lane >= o) s += u;
  }
  __shared__ int wsum[4];
  if (lane == 63) wsum[w] = s;
  __syncthreads();
  int add = 0;
  for (int i = 0; i < w; ++i) add += wsum[i];
  const int incl = s + add;
  if (idx < NN) cnt[idx] = incl - v;  // exclusive
  if (threadIdx.x == 255) bsum[blockIdx.x] = incl;
}

// pass 2: single-block exclusive scan of the NB block totals
__global__ __launch_bounds__(512) void k_scan2(int* __restrict__ bsum) {
  const int t = threadIdx.x;
  const int v = (t < NB) ? bsum[t] : 0;
  const int lane = t & 63;
  const int w = t >> 6;
  int s = v;
#pragma unroll
  for (int o = 1; o < 64; o <<= 1) {
    int u = __shfl_up(s, o);
    if (lane >= o) s += u;
  }
  __shared__ int wsum[8];
  if (lane == 63) wsum[w] = s;
  __syncthreads();
  int add = 0;
  for (int i = 0; i < w; ++i) add += wsum[i];
  if (t < NB) bsum[t] = s + add - v;  // exclusive
}

// pass 3: add block offsets; snapshot cursor
__global__ __launch_bounds__(256) void k_scan3(int* __restrict__ cnt,
                                               const int* __restrict__ bsum,
                                               int* __restrict__ cursor) {
  const int idx = blockIdx.x * 256 + threadIdx.x;
  if (idx < NN) {
    const int o = cnt[idx] + bsum[blockIdx.x];
    cnt[idx] = o;
    cursor[idx] = o;
  }
}

// place src ids into dst-sorted order
__global__ __launch_bounds__(256) void k_place(const int* __restrict__ src,
                                               const int* __restrict__ dst,
                                               int* __restrict__ cursor,
                                               int* __restrict__ srcs) {
  int e = blockIdx.x * 256 + threadIdx.x;
  if (e < NE) {
    const int pos = atomicAdd(&cursor[dst[e]], 1);
    srcs[pos] = src[e];
  }
}

// --------------------------------------------- gather-based aggregation
// one wave per dst node; lane handles 2 consecutive feats (512B/row coalesced)
__global__ __launch_bounds__(256) void k_agg(const float* __restrict__ feat,
                                             const int* __restrict__ offs,
                                             const int* __restrict__ srcs,
                                             float* __restrict__ out) {
  const int node = blockIdx.x * 4 + (threadIdx.x >> 6);
  if (node >= NN) return;
  const int lane = threadIdx.x & 63;
  const int c = lane * 2;
  const int beg = offs[node];
  const int end = (node == NN - 1) ? NE : offs[node + 1];

  float a0x = 0.f, a0y = 0.f, a1x = 0.f, a1y = 0.f;
  float a2x = 0.f, a2y = 0.f, a3x = 0.f, a3y = 0.f;
  int e = beg;
  for (; e + 4 <= end; e += 4) {
    const int s0 = srcs[e], s1 = srcs[e + 1], s2 = srcs[e + 2], s3 = srcs[e + 3];
    const float2 v0 = *reinterpret_cast<const float2*>(feat + (size_t)s0 * NF + c);
    const float2 v1 = *reinterpret_cast<const float2*>(feat + (size_t)s1 * NF + c);
    const float2 v2 = *reinterpret_cast<const float2*>(feat + (size_t)s2 * NF + c);
    const float2 v3 = *reinterpret_cast<const float2*>(feat + (size_t)s3 * NF + c);
    a0x += v0.x; a0y += v0.y;
    a1x += v1.x; a1y += v1.y;
    a2x += v2.x; a2y += v2.y;
    a3x += v3.x; a3y += v3.y;
  }
  for (; e < end; ++e) {
    const int s = srcs[e];
    const float2 v = *reinterpret_cast<const float2*>(feat + (size_t)s * NF + c);
    a0x += v.x; a0y += v.y;
  }
  float2 r;
  r.x = (a0x + a1x) + (a2x + a3x);
  r.y = (a0y + a1y) + (a2y + a3y);
  *reinterpret_cast<float2*>(out + (size_t)node * NF + c) = r;
}

// ---------------------------------------------------------------- fused GEMM
// out[i][j] = relu( A1[i,:]·B1[j,:] + A2[i,:]·B2[j,:] + bias[j] ), K=128 each.
// Tile: 64 nodes x 128 outputs, BK=32, 256 threads, 32 acc/thread.
// In-place safe: each block reads only the A-rows it writes.
template <int RELU>
__global__ __launch_bounds__(256) void k_gemm(const float* __restrict__ A1,
                                              const float* __restrict__ A2,
                                              const float* __restrict__ B1,
                                              const float* __restrict__ B2,
                                              const float* __restrict__ bias,
                                              float* __restrict__ out) {
  __shared__ __align__(16) float At[32][72];
  __shared__ __align__(16) float Bt[32][136];

  const int tid = threadIdx.x;
  const int n0 = blockIdx.x * 64;
  const int tx = tid & 15;
  const int ty = tid >> 4;

  float acc[4][8];
#pragma unroll
  for (int r = 0; r < 4; ++r)
#pragma unroll
    for (int c = 0; c < 8; ++c) acc[r][c] = 0.f;

  const int li = tid >> 2;
  const int lq = tid & 3;
  const int bj = tid >> 1;
  const int bh = tid & 1;

  for (int k0 = 0; k0 < 256; k0 += 32) {
    const float* __restrict__ A = (k0 < 128) ? A1 : A2;
    const float* __restrict__ B = (k0 < 128) ? B1 : B2;
    const int kb = k0 & 127;

    {
      float4 v0 = make_float4(0.f, 0.f, 0.f, 0.f), v1 = v0;
      const int node = n0 + li;
      if (node < NN) {
        const float* p = A + (size_t)node * NF + kb + lq * 8;
        v0 = *reinterpret_cast<const float4*>(p);
        v1 = *reinterpret_cast<const float4*>(p + 4);
      }
      const int kk = lq * 8;
      At[kk + 0][li] = v0.x; At[kk + 1][li] = v0.y;
      At[kk + 2][li] = v0.z; At[kk + 3][li] = v0.w;
      At[kk + 4][li] = v1.x; At[kk + 5][li] = v1.y;
      At[kk + 6][li] = v1.z; At[kk + 7][li] = v1.w;
    }
    {
      const float* p = B + (size_t)bj * NF + kb + bh * 16;
      const float4 w0 = *reinterpret_cast<const float4*>(p);
      const float4 w1 = *reinterpret_cast<const float4*>(p + 4);
      const float4 w2 = *reinterpret_cast<const float4*>(p + 8);
      const float4 w3 = *reinterpret_cast<const float4*>(p + 12);
      const int kk = bh * 16;
      Bt[kk + 0][bj] = w0.x;  Bt[kk + 1][bj] = w0.y;
      Bt[kk + 2][bj] = w0.z;  Bt[kk + 3][bj] = w0.w;
      Bt[kk + 4][bj] = w1.x;  Bt[kk + 5][bj] = w1.y;
      Bt[kk + 6][bj] = w1.z;  Bt[kk + 7][bj] = w1.w;
      Bt[kk + 8][bj] = w2.x;  Bt[kk + 9][bj] = w2.y;
      Bt[kk + 10][bj] = w2.z; Bt[kk + 11][bj] = w2.w;
      Bt[kk + 12][bj] = w3.x; Bt[kk + 13][bj] = w3.y;
      Bt[kk + 14][bj] = w3.z; Bt[kk + 15][bj] = w3.w;
    }
    __syncthreads();

#pragma unroll
    for (int kk = 0; kk < 32; ++kk) {
      const float4 a = *reinterpret_cast<const float4*>(&At[kk][ty * 4]);
      const float4 b0 = *reinterpret_cast<const float4*>(&Bt[kk][tx * 4]);
      const float4 b1 = *reinterpret_cast<const float4*>(&Bt[kk][64 + tx * 4]);
      const float av[4] = {a.x, a.y, a.z, a.w};
      const float bv[8] = {b0.x, b0.y, b0.z, b0.w, b1.x, b1.y, b1.z, b1.w};
#pragma unroll
      for (int r = 0; r < 4; ++r)
#pragma unroll
        for (int c = 0; c < 8; ++c) acc[r][c] += av[r] * bv[c];
    }
    __syncthreads();
  }

  float bv[8];
#pragma unroll
  for (int c = 0; c < 4; ++c) {
    bv[c] = bias[tx * 4 + c];
    bv[4 + c] = bias[64 + tx * 4 + c];
  }
#pragma unroll
  for (int r = 0; r < 4; ++r) {
    const int node = n0 + ty * 4 + r;
    if (node < NN) {
      float4 o0, o1;
      o0.x = acc[r][0] + bv[0]; o0.y = acc[r][1] + bv[1];
      o0.z = acc[r][2] + bv[2]; o0.w = acc[r][3] + bv[3];
      o1.x = acc[r][4] + bv[4]; o1.y = acc[r][5] + bv[5];
      o1.z = acc[r][6] + bv[6]; o1.w = acc[r][7] + bv[7];
      if (RELU) {
        o0.x = fmaxf(o0.x, 0.f); o0.y = fmaxf(o0.y, 0.f);
        o0.z = fmaxf(o0.z, 0.f); o0.w = fmaxf(o0.w, 0.f);
        o1.x = fmaxf(o1.x, 0.f); o1.y = fmaxf(o1.y, 0.f);
        o1.z = fmaxf(o1.z, 0.f); o1.w = fmaxf(o1.w, 0.f);
      }
      float* po = out + (size_t)node * NF;
      *reinterpret_cast<float4*>(po + tx * 4) = o0;
      *reinterpret_cast<float4*>(po + 64 + tx * 4) = o1;
    }
  }
}

// ------------------------------------- layer-3 collapsed weighted reductions
__global__ __launch_bounds__(256) void k_reduce3(const float* __restrict__ h,
                                                 const int* __restrict__ deg,
                                                 float* __restrict__ S) {
  const int t = blockIdx.x * 256 + threadIdx.x;
  const int f = t & 127;
  const int i0 = t >> 7;
  float a1 = 0.f, a2 = 0.f;
  for (int i = i0; i < NN; i += 512) {
    const float v = h[(size_t)i * NF + f];
    a1 += v;
    a2 += (float)deg[i] * v;
  }
  atomicAdd(&S[f], a1);
  atomicAdd(&S[128 + f], a2);
}

__global__ __launch_bounds__(128) void k_final(const float* __restrict__ S,
                                               const float* __restrict__ W3rel,
                                               const float* __restrict__ W3root,
                                               const float* __restrict__ b3,
                                               float* __restrict__ out) {
  const int f = threadIdx.x;
  float v = W3rel[f] * S[128 + f] + W3root[f] * S[f];
#pragma unroll
  for (int o = 32; o > 0; o >>= 1) v += __shfl_down(v, o);
  __shared__ float tmp[2];
  if ((f & 63) == 0) tmp[f >> 6] = v;
  __syncthreads();
  if (f == 0) out[0] = (tmp[0] + tmp[1]) * (1.0f / NN) + b3[0];
}

// ---------------------------------------------------------------------------
extern "C" void kernel_launch(void* const* d_in, const int* in_sizes, int n_in,
                              void* d_out, int out_size, void* d_ws, size_t ws_size,
                              hipStream_t stream) {
  const float* x = (const float*)d_in[0];
  const int* ei = (const int*)d_in[1];
  const float* W1rel = (const float*)d_in[2];
  const float* b1 = (const float*)d_in[3];
  const float* W1root = (const float*)d_in[4];
  const float* W2rel = (const float*)d_in[5];
  const float* b2 = (const float*)d_in[6];
  const float* W2root = (const float*)d_in[7];
  const float* W3rel = (const float*)d_in[8];
  const float* b3 = (const float*)d_in[9];
  const float* W3root = (const float*)d_in[10];

  const int* src = ei;       // edge_index[0]
  const int* dst = ei + NE;  // edge_index[1]

  char* ws = (char*)d_ws;
  size_t off = 0;
  float* bufA = (float*)(ws + off); off += (size_t)NN * NF * 4;   // 51.2 MB
  float* bufB = (float*)(ws + off); off += (size_t)NN * NF * 4;   // 51.2 MB
  int* offs   = (int*)(ws + off);   off += (size_t)NN * 4;        // 400 KB
  int* cursor = (int*)(ws + off);   off += (size_t)NN * 4;        // 400 KB
  int* deg    = (int*)(ws + off);   off += (size_t)NN * 4;        // 400 KB
  int* bsum   = (int*)(ws + off);   off += 512 * 4;               // 2 KB
  float* S    = (float*)(ws + off); off += 256 * 4;               // 1 KB
  int* srcs   = (int*)(ws + off);   off += (size_t)NE * 4;        // 6.4 MB
  float* outp = (float*)d_out;

  hipMemsetAsync(offs, 0, (size_t)NN * sizeof(int), stream);
  hipMemsetAsync(deg, 0, (size_t)NN * sizeof(int), stream);
  hipMemsetAsync(S, 0, 256 * sizeof(float), stream);

  // build dst-sorted CSR
  k_hist<<<(NE + 255) / 256, 256, 0, stream>>>(dst, offs);
  k_scan1<<<NB, 256, 0, stream>>>(offs, bsum);
  k_scan2<<<1, 512, 0, stream>>>(bsum);
  k_scan3<<<NB, 256, 0, stream>>>(offs, bsum, cursor);
  k_place<<<(NE + 255) / 256, 256, 0, stream>>>(src, dst, cursor, srcs);
  k_deg<<<(NE + 255) / 256, 256, 0, stream>>>(src, deg);

  // layer 1: agg(x) -> bufA; h1 = relu(gemm) in-place into bufA
  k_agg<<<(NN + 3) / 4, 256, 0, stream>>>(x, offs, srcs, bufA);
  k_gemm<1><<<(NN + 63) / 64, 256, 0, stream>>>(bufA, x, W1rel, W1root, b1, bufA);

  // layer 2: agg(h1) -> bufB; h2 = relu(gemm) in-place into bufB
  k_agg<<<(NN + 3) / 4, 256, 0, stream>>>(bufA, offs, srcs, bufB);
  k_gemm<1><<<(NN + 63) / 64, 256, 0, stream>>>(bufB, bufA, W2rel, W2root, b2, bufB);

  // layer 3 collapsed
  k_reduce3<<<256, 256, 0, stream>>>(bufB, deg, S);
  k_final<<<1, 128, 0, stream>>>(S, W3rel, W3root, b3, outp);
}